// Round 10
// baseline (636.609 us; speedup 1.0000x reference)
//
#include <hip/hip_runtime.h>
#include <hip/hip_bf16.h>

typedef __attribute__((ext_vector_type(4))) float f32x4;
typedef __attribute__((ext_vector_type(8))) short s16x8;
typedef __attribute__((ext_vector_type(2))) unsigned int u32x2;
typedef __attribute__((ext_vector_type(4))) unsigned int u32x4;

#define DEV static __device__ __forceinline__

constexpr int Tn = 256, Bn = 1024, Sn = 8;
constexpr float L2E   =  1.44269504f;
constexpr float NL2E  = -1.44269504f;   // fold into sigmoid-arg weights
constexpr float N2L2E = -2.88539008f;   // fold into tanh-arg weights

struct Params {
  const float* obs; const float* enc_w; const float* enc_b;
  const float* mw[15];            // wW wI wA zW zI zA rW rI rA hW hI hA aW aI aA
  const float* gw[4];             // att wmg img amg  [32 x 64]
  const float* gb[4];
  const float* z_b; const float* r_b; const float* h_b; const float* a_b;
  const float* phi_w; const float* phi_b;
  float* out;
};

DEV f32x4 ld4(const float* p) { return *(const f32x4*)p; }
DEV f32x4 zero4() { f32x4 r = {0.f,0.f,0.f,0.f}; return r; }
DEV s16x8 zero8() { s16x8 r = {0,0,0,0,0,0,0,0}; return r; }

// packed f32->bf16 pair (RNE) -> v_cvt_pk_bf16_f32
DEV unsigned cvtpk(float a, float b) {
  __hip_bfloat162 t = __float22bfloat162_rn(make_float2(a, b));
  unsigned u; __builtin_memcpy(&u, &t, 4);
  return u;
}

// pack 8 scaled f32 into a bf16x8 fragment; elem e=0..3 <-> k=4h+e,
// e=4..7 <-> k=16+4h+(e-4)  [same k-map lambda on A and B sides]
DEV s16x8 pk2s(f32x4 a, f32x4 b, float s) {
  u32x4 f;
  f[0] = cvtpk(a[0]*s, a[1]*s); f[1] = cvtpk(a[2]*s, a[3]*s);
  f[2] = cvtpk(b[0]*s, b[1]*s); f[3] = cvtpk(b[2]*s, b[3]*s);
  s16x8 r; __builtin_memcpy(&r, &f, 16);
  return r;
}

// weight fragment (A-operand of swapped MFMA): lane (h,c) holds matrix row
// `row`, k-cols {kofs+4h..+3, kofs+16+4h..+3}; values pre-scaled by s.
DEV s16x8 wfrag(const float* w, int row, int ldk, int kofs, int h, float s) {
  const float* p = w + row*ldk + kofs + 4*h;
  return pk2s(ld4(p), ld4(p+16), s);
}

DEV f32x4 MF(s16x8 a, s16x8 b, f32x4 c) {
  return __builtin_amdgcn_mfma_f32_16x16x32_bf16(a, b, c, 0, 0, 0);
}

DEV float ex2(float x)  { return __builtin_amdgcn_exp2f(x); }
DEV float rcp_(float x) { return __builtin_amdgcn_rcpf(x); }
// activations with the scale already folded into the argument:
DEV float sg(float a) { return rcp_(1.f + ex2(a)); }                 // sigmoid(x), a=-L2E*x
DEV float th(float a) { return fmaf(rcp_(1.f + ex2(a)), 2.f, -1.f); } // tanh(x), a=-2L2E*x

DEV unsigned long long pack64(u32x2 v) {
  return ((unsigned long long)v[1] << 32) | v[0];
}
DEV u32x2 unpack64(unsigned long long x) {
  u32x2 r; r[0] = (unsigned)x; r[1] = (unsigned)(x >> 32); return r;
}
DEV u32x2 pkx(f32x4 v) {
  u32x2 r; r[0] = cvtpk(v[0], v[1]); r[1] = cvtpk(v[2], v[3]); return r;
}
// assemble full 32-k state fragment from own half + partner half
DEV s16x8 frag(u32x2 own, u32x2 oth, int wv) {
  u32x4 f;
  if (wv == 0) { f[0]=own[0]; f[1]=own[1]; f[2]=oth[0]; f[3]=oth[1]; }
  else         { f[0]=oth[0]; f[1]=oth[1]; f[2]=own[0]; f[3]=own[1]; }
  s16x8 r; __builtin_memcpy(&r, &f, 16);
  return r;
}

DEV f32x4 scl4(f32x4 v, float s) { f32x4 r; r[0]=v[0]*s; r[1]=v[1]*s; r[2]=v[2]*s; r[3]=v[3]*s; return r; }

// 2 waves per block, 2 independent batch chains (Q=2) interleaved per wave for
// ILP: chain q owns batch rows [bbase+16q, bbase+16q+16). Wave w owns output
// dims [16w, 16w+16) of both chains. Packed bf16 state halves exchanged via
// LDS (8B/lane, partner = tid^64), one barrier per phase shared by both chains.
__global__ __launch_bounds__(128, 1) void anima_kernel(Params P) {
  const int tid  = threadIdx.x;
  const int wv   = tid >> 6;
  const int lane = tid & 63;
  const int h = lane >> 4, c = lane & 15;
  const int bbase = blockIdx.x * 32;
  const int row = wv*16 + c;

  __shared__ unsigned long long xb[4][2][128];

  // ---- persistent weight fragments, own j-half only, scale pre-folded ----
  const float msc[15] = {N2L2E,N2L2E,N2L2E,  NL2E,NL2E,NL2E,  NL2E,NL2E,NL2E,
                         N2L2E,N2L2E,N2L2E,  N2L2E,N2L2E,N2L2E};
  s16x8 m[15];
#pragma unroll
  for (int i = 0; i < 15; ++i) m[i] = wfrag(P.mw[i], row, 32, 0, h, msc[i]);

  s16x8 g[4][2];   // att wmg img amg, k-chunks q=0,1
#pragma unroll
  for (int i = 0; i < 4; ++i)
#pragma unroll
    for (int q = 0; q < 2; ++q)
      g[i][q] = wfrag(P.gw[i], row, 64, 32*q, h, NL2E);

  s16x8 ef = zero8();          // encoder rows own-j, k 0..7 on h<2 lanes
  if (h < 2) { f32x4 v = ld4(P.enc_w + row*Sn + 4*h); ef = pk2s(v, zero4(), N2L2E); }

  s16x8 pf = (wv == 0 && c < 4) ? wfrag(P.phi_w, c, 32, 0, h, 1.0f) : zero8();

  const int o = wv*16 + 4*h;   // bias accum-init: outdim 16w+4h+r
  f32x4 bE  = scl4(ld4(P.enc_b + o), N2L2E);
  f32x4 bAt = scl4(ld4(P.gb[0] + o), NL2E);
  f32x4 bMu = scl4(ld4(P.gb[1] + o), NL2E);
  f32x4 bMI = scl4(ld4(P.gb[2] + o), NL2E);
  f32x4 bMA = scl4(ld4(P.gb[3] + o), NL2E);
  f32x4 bZ  = scl4(ld4(P.z_b + o),  NL2E);
  f32x4 bR  = scl4(ld4(P.r_b + o),  NL2E);
  f32x4 bH  = scl4(ld4(P.h_b + o),  N2L2E);
  f32x4 bA  = scl4(ld4(P.a_b + o),  N2L2E);
  f32x4 pb  = (wv == 0 && h == 0) ? ld4(P.phi_b) : zero4();

  // ---- per-chain state: I fp32 (own 4 dims), full bf16 frags for W/I/A ----
  f32x4 iv[2]; s16x8 Wf[2], If[2], Af[2]; f32x4 ob[2];
#pragma unroll
  for (int q = 0; q < 2; ++q) {
    iv[q] = zero4(); Wf[q] = zero8(); If[q] = zero8(); Af[q] = zero8();
    ob[q] = zero4();
    if (h < 2) ob[q] = ld4(P.obs + (size_t)(bbase + q*16 + c) * Sn + 4*h);
  }

#pragma unroll 1
  for (int t = 0; t < Tn; ++t) {
    s16x8 Of[2]; f32x4 nb[2];
#pragma unroll
    for (int q = 0; q < 2; ++q) {
      Of[q] = (h < 2) ? pk2s(ob[q], zero4(), 1.0f) : zero8();
      nb[q] = ob[q];
      if (h < 2 && t + 1 < Tn)
        nb[q] = ld4(P.obs + ((size_t)(t+1)*Bn + bbase + q*16 + c) * Sn + 4*h);
    }

    // ---- phase A: W_all, att, wmg, enc (own j-half, both chains) ----
    s16x8 Wnf[2];
    {
      f32x4 aWl[2], aAt[2], aMu[2], aE[2];
#pragma unroll
      for (int q = 0; q < 2; ++q) {
        f32x4 x = MF(m[0], Wf[q], zero4()); x = MF(m[1], If[q], x); aWl[q] = MF(m[2], Af[q], x);
        f32x4 y = MF(g[0][0], Wf[q], bAt);  aAt[q] = MF(g[0][1], If[q], y);
        f32x4 u = MF(g[1][0], If[q], bMu);  aMu[q] = MF(g[1][1], Af[q], u);
        aE[q]  = MF(ef, Of[q], bE);
      }
      u32x2 wn2[2];
#pragma unroll
      for (int q = 0; q < 2; ++q) {
        f32x4 wn;
#pragma unroll
        for (int r = 0; r < 4; ++r) {
          float etp = fmaf(rcp_(1.f + ex2(aE[q][r])), -4.f*L2E, 2.f*L2E);  // -2L2E*tanh(enc)
          float at  = sg(aAt[q][r]);
          float mg  = sg(aMu[q][r]);
          float wp  = fmaf(etp, at, aWl[q][r]*mg);                          // -2L2E*Wn_pre
          wn[r] = th(wp);
        }
        wn2[q] = pkx(wn);
        xb[0][q][tid] = pack64(wn2[q]);
      }
      __syncthreads();
#pragma unroll
      for (int q = 0; q < 2; ++q) Wnf[q] = frag(wn2[q], unpack64(xb[0][q][tid ^ 64]), wv);
    }

    // ---- phase B: z, r, mult_I (both chains) ----
    f32x4 zz[2], mi[2]; s16x8 rIf[2];
    {
      f32x4 aZ[2], aR[2], aMI[2];
#pragma unroll
      for (int q = 0; q < 2; ++q) {
        f32x4 x = MF(m[3], Wnf[q], bZ); x = MF(m[4], If[q], x); aZ[q] = MF(m[5], Af[q], x);
        f32x4 y = MF(m[6], Wnf[q], bR); y = MF(m[7], If[q], y); aR[q] = MF(m[8], Af[q], y);
        f32x4 u = MF(g[2][0], Wnf[q], bMI); aMI[q] = MF(g[2][1], Af[q], u);   // img over [W_new, A]
      }
      u32x2 ri2[2];
#pragma unroll
      for (int q = 0; q < 2; ++q) {
        f32x4 ri;
#pragma unroll
        for (int r = 0; r < 4; ++r) {
          zz[q][r] = sg(aZ[q][r]);
          ri[r]    = sg(aR[q][r]) * iv[q][r];
          mi[q][r] = sg(aMI[q][r]);
        }
        ri2[q] = pkx(ri);
        xb[1][q][tid] = pack64(ri2[q]);
      }
      __syncthreads();
#pragma unroll
      for (int q = 0; q < 2; ++q) rIf[q] = frag(ri2[q], unpack64(xb[1][q][tid ^ 64]), wv);
    }

    // ---- phase C: h, I_new (both chains) ----
    f32x4 inw[2]; s16x8 Inf[2];
    {
      f32x4 aH[2];
#pragma unroll
      for (int q = 0; q < 2; ++q) {
        f32x4 x = MF(m[9], Wnf[q], bH); x = MF(m[10], rIf[q], x); aH[q] = MF(m[11], Af[q], x);
      }
      u32x2 in2[2];
#pragma unroll
      for (int q = 0; q < 2; ++q) {
#pragma unroll
        for (int r = 0; r < 4; ++r) {
          float hv = th(aH[q][r]);
          float tt = hv * mi[q][r];
          inw[q][r] = fmaf(zz[q][r], tt - iv[q][r], iv[q][r]);   // (1-z)*iv + z*h*mi
        }
        in2[q] = pkx(inw[q]);
        xb[2][q][tid] = pack64(in2[q]);
      }
      __syncthreads();
#pragma unroll
      for (int q = 0; q < 2; ++q) Inf[q] = frag(in2[q], unpack64(xb[2][q][tid ^ 64]), wv);
    }

    // ---- phase D: A_all, mult_A, A_new (both chains) ----
    s16x8 Anf[2];
    {
      f32x4 aAl[2], aMA[2];
#pragma unroll
      for (int q = 0; q < 2; ++q) {
        f32x4 x = MF(m[12], Wnf[q], bA); x = MF(m[13], Inf[q], x); aAl[q] = MF(m[14], Af[q], x);
        f32x4 y = MF(g[3][0], Wnf[q], bMA); aMA[q] = MF(g[3][1], Inf[q], y);  // amg over [W_new, I_new]
      }
      u32x2 an2[2];
#pragma unroll
      for (int q = 0; q < 2; ++q) {
        f32x4 an;
#pragma unroll
        for (int r = 0; r < 4; ++r) an[r] = th(aAl[q][r] * sg(aMA[q][r]));
        an2[q] = pkx(an);
        xb[3][q][tid] = pack64(an2[q]);
      }
      __syncthreads();
#pragma unroll
      for (int q = 0; q < 2; ++q) Anf[q] = frag(an2[q], unpack64(xb[3][q][tid ^ 64]), wv);
    }

    // ---- phase E: action = phi(A_new) + phi_b (wave0; h=0 lanes -> out[c][0..4)) ----
    if (wv == 0) {
#pragma unroll
      for (int q = 0; q < 2; ++q) {
        f32x4 aP = MF(pf, Anf[q], pb);
        if (h == 0)
          *(f32x4*)(P.out + ((size_t)t*Bn + bbase + q*16 + c) * 4) = aP;
      }
    }

    // ---- rotate state ----
#pragma unroll
    for (int q = 0; q < 2; ++q) {
      Wf[q] = Wnf[q]; If[q] = Inf[q]; Af[q] = Anf[q]; iv[q] = inw[q]; ob[q] = nb[q];
    }
  }
}

extern "C" void kernel_launch(void* const* d_in, const int* in_sizes, int n_in,
                              void* d_out, int out_size, void* d_ws, size_t ws_size,
                              hipStream_t stream) {
  (void)in_sizes; (void)n_in; (void)d_ws; (void)ws_size; (void)out_size;
  Params p;
  p.obs   = (const float*)d_in[0];
  p.enc_w = (const float*)d_in[1];
  p.enc_b = (const float*)d_in[2];
  for (int i = 0; i < 15; ++i) p.mw[i] = (const float*)d_in[3 + i];
  for (int i = 0; i < 4; ++i) {
    p.gw[i] = (const float*)d_in[18 + 2*i];
    p.gb[i] = (const float*)d_in[19 + 2*i];
  }
  p.z_b   = (const float*)d_in[26];
  p.r_b   = (const float*)d_in[27];
  p.h_b   = (const float*)d_in[28];
  p.a_b   = (const float*)d_in[29];
  p.phi_w = (const float*)d_in[30];
  p.phi_b = (const float*)d_in[31];
  p.out   = (float*)d_out;

  hipLaunchKernelGGL(anima_kernel, dim3(Bn / 32), dim3(128), 0, stream, p);
}

// Round 11
// 548.836 us; speedup vs baseline: 1.1599x; 1.1599x over previous
//
#include <hip/hip_runtime.h>
#include <hip/hip_bf16.h>

typedef __attribute__((ext_vector_type(4))) float f32x4;
typedef __attribute__((ext_vector_type(8))) short s16x8;
typedef __attribute__((ext_vector_type(2))) unsigned int u32x2;
typedef __attribute__((ext_vector_type(4))) unsigned int u32x4;

#define DEV static __device__ __forceinline__

constexpr int Tn = 256, Bn = 1024, Sn = 8;
constexpr float L2E   =  1.44269504f;
constexpr float NL2E  = -1.44269504f;   // fold into sigmoid-arg weights
constexpr float N2L2E = -2.88539008f;   // fold into tanh-arg weights

struct Params {
  const float* obs; const float* enc_w; const float* enc_b;
  const float* mw[15];            // wW wI wA zW zI zA rW rI rA hW hI hA aW aI aA
  const float* gw[4];             // att wmg img amg  [32 x 64]
  const float* gb[4];
  const float* z_b; const float* r_b; const float* h_b; const float* a_b;
  const float* phi_w; const float* phi_b;
  float* out;
};

DEV f32x4 ld4(const float* p) { return *(const f32x4*)p; }
DEV f32x4 zero4() { f32x4 r = {0.f,0.f,0.f,0.f}; return r; }
DEV s16x8 zero8() { s16x8 r = {0,0,0,0,0,0,0,0}; return r; }

// packed f32->bf16 pair (RNE) -> v_cvt_pk_bf16_f32
DEV unsigned cvtpk(float a, float b) {
  __hip_bfloat162 t = __float22bfloat162_rn(make_float2(a, b));
  unsigned u; __builtin_memcpy(&u, &t, 4);
  return u;
}

// pack 8 scaled f32 into a bf16x8 fragment; elem e=0..3 <-> k=4h+e,
// e=4..7 <-> k=16+4h+(e-4)  [same k-map lambda on A and B sides]
DEV s16x8 pk2s(f32x4 a, f32x4 b, float s) {
  u32x4 f;
  f[0] = cvtpk(a[0]*s, a[1]*s); f[1] = cvtpk(a[2]*s, a[3]*s);
  f[2] = cvtpk(b[0]*s, b[1]*s); f[3] = cvtpk(b[2]*s, b[3]*s);
  s16x8 r; __builtin_memcpy(&r, &f, 16);
  return r;
}

// weight fragment (A-operand of swapped MFMA): lane (h,c) holds matrix row
// `row`, k-cols {kofs+4h..+3, kofs+16+4h..+3}; values pre-scaled by s.
DEV s16x8 wfrag(const float* w, int row, int ldk, int kofs, int h, float s) {
  const float* p = w + row*ldk + kofs + 4*h;
  return pk2s(ld4(p), ld4(p+16), s);
}

DEV f32x4 MF(s16x8 a, s16x8 b, f32x4 c) {
  return __builtin_amdgcn_mfma_f32_16x16x32_bf16(a, b, c, 0, 0, 0);
}

DEV float ex2(float x)  { return __builtin_amdgcn_exp2f(x); }
DEV float rcp_(float x) { return __builtin_amdgcn_rcpf(x); }
// activations with the scale already folded into the argument:
DEV float sg(float a) { return rcp_(1.f + ex2(a)); }                 // sigmoid(x), a=-L2E*x
DEV float th(float a) { return fmaf(rcp_(1.f + ex2(a)), 2.f, -1.f); } // tanh(x), a=-2L2E*x

DEV unsigned long long pack64(u32x2 v) {
  return ((unsigned long long)v[1] << 32) | v[0];
}
DEV u32x2 unpack64(unsigned long long x) {
  u32x2 r; r[0] = (unsigned)x; r[1] = (unsigned)(x >> 32); return r;
}
DEV u32x2 pkx(f32x4 v) {
  u32x2 r; r[0] = cvtpk(v[0], v[1]); r[1] = cvtpk(v[2], v[3]); return r;
}
// assemble full 32-k state fragment from own half + partner half
DEV s16x8 frag(u32x2 own, u32x2 oth, int wv) {
  u32x4 f;
  if (wv == 0) { f[0]=own[0]; f[1]=own[1]; f[2]=oth[0]; f[3]=oth[1]; }
  else         { f[0]=oth[0]; f[1]=oth[1]; f[2]=own[0]; f[3]=own[1]; }
  s16x8 r; __builtin_memcpy(&r, &f, 16);
  return r;
}

DEV f32x4 scl4(f32x4 v, float s) { f32x4 r; r[0]=v[0]*s; r[1]=v[1]*s; r[2]=v[2]*s; r[3]=v[3]*s; return r; }

// 512-thread blocks = 4 independent wave-PAIRS per block (one pair per 16
// batch rows, same structure as the 294us round-8 kernel). Purpose: 8 waves
// per CU = 2 waves/SIMD so the in-order SIMD can interleave two waves'
// instruction streams and fill each other's latency bubbles (TLP, not ILP —
// the round-10 ILP attempt serialized inside one in-order wave).
// Block-wide barriers sync all 4 pairs; symmetric code => minimal skew cost.
__global__ __launch_bounds__(512, 1) void anima_kernel(Params P) {
  const int tid  = threadIdx.x;          // 0..511
  const int pr   = tid >> 7;             // pair 0..3
  const int wv   = (tid >> 6) & 1;       // wave-in-pair
  const int lane = tid & 63;
  const int h = lane >> 4, c = lane & 15;
  const int bbase = blockIdx.x * 64 + pr * 16;
  const int row = wv*16 + c;

  __shared__ unsigned long long xb[4][512];

  // ---- persistent weight fragments, own j-half only, scale pre-folded ----
  const float msc[15] = {N2L2E,N2L2E,N2L2E,  NL2E,NL2E,NL2E,  NL2E,NL2E,NL2E,
                         N2L2E,N2L2E,N2L2E,  N2L2E,N2L2E,N2L2E};
  s16x8 m[15];
#pragma unroll
  for (int i = 0; i < 15; ++i) m[i] = wfrag(P.mw[i], row, 32, 0, h, msc[i]);

  s16x8 g[4][2];   // att wmg img amg, k-chunks q=0,1
#pragma unroll
  for (int i = 0; i < 4; ++i)
#pragma unroll
    for (int q = 0; q < 2; ++q)
      g[i][q] = wfrag(P.gw[i], row, 64, 32*q, h, NL2E);

  s16x8 ef = zero8();          // encoder rows own-j, k 0..7 on h<2 lanes
  if (h < 2) { f32x4 v = ld4(P.enc_w + row*Sn + 4*h); ef = pk2s(v, zero4(), N2L2E); }

  s16x8 pf = (wv == 0 && c < 4) ? wfrag(P.phi_w, c, 32, 0, h, 1.0f) : zero8();

  const int o = wv*16 + 4*h;   // bias accum-init: outdim 16w+4h+r
  f32x4 bE  = scl4(ld4(P.enc_b + o), N2L2E);
  f32x4 bAt = scl4(ld4(P.gb[0] + o), NL2E);
  f32x4 bMu = scl4(ld4(P.gb[1] + o), NL2E);
  f32x4 bMI = scl4(ld4(P.gb[2] + o), NL2E);
  f32x4 bMA = scl4(ld4(P.gb[3] + o), NL2E);
  f32x4 bZ  = scl4(ld4(P.z_b + o),  NL2E);
  f32x4 bR  = scl4(ld4(P.r_b + o),  NL2E);
  f32x4 bH  = scl4(ld4(P.h_b + o),  N2L2E);
  f32x4 bA  = scl4(ld4(P.a_b + o),  N2L2E);
  f32x4 pb  = (wv == 0 && h == 0) ? ld4(P.phi_b) : zero4();

  // ---- state: I fp32 (own 4 dims), full bf16 fragments for W/I/A ----
  f32x4 iv = zero4();
  s16x8 Wf = zero8(), If = zero8(), Af = zero8();

  f32x4 ob = zero4();
  if (h < 2) ob = ld4(P.obs + (size_t)(bbase + c) * Sn + 4*h);

#pragma unroll 1
  for (int t = 0; t < Tn; ++t) {
    s16x8 Of = (h < 2) ? pk2s(ob, zero4(), 1.0f) : zero8();
    f32x4 nb = ob;
    if (h < 2 && t + 1 < Tn)
      nb = ld4(P.obs + ((size_t)(t+1)*Bn + bbase + c) * Sn + 4*h);

    // ---- phase A: W_all, att, wmg, enc (own j-half) ----
    f32x4 x = MF(m[0], Wf, zero4()); x = MF(m[1], If, x); f32x4 aWl = MF(m[2], Af, x); // -2L2E*Wall
    f32x4 y = MF(g[0][0], Wf, bAt);  f32x4 aAt = MF(g[0][1], If, y);                   // -L2E*attpre
    f32x4 u = MF(g[1][0], If, bMu);  f32x4 aMu = MF(g[1][1], Af, u);                   // -L2E*wmgpre
    f32x4 aE = MF(ef, Of, bE);                                                          // -2L2E*encpre
    f32x4 wn;
#pragma unroll
    for (int r = 0; r < 4; ++r) {
      float etp = fmaf(rcp_(1.f + ex2(aE[r])), -4.f*L2E, 2.f*L2E);  // -2L2E*tanh(enc)
      float at  = sg(aAt[r]);
      float mg  = sg(aMu[r]);
      float wp  = fmaf(etp, at, aWl[r]*mg);                          // -2L2E*Wn_pre
      wn[r] = th(wp);
    }
    u32x2 wn2 = pkx(wn);
    xb[0][tid] = pack64(wn2); __syncthreads();
    s16x8 Wnf = frag(wn2, unpack64(xb[0][tid ^ 64]), wv);

    // ---- phase B: z, r, mult_I ----
    x = MF(m[3], Wnf, bZ); x = MF(m[4], If, x); f32x4 aZ = MF(m[5], Af, x);
    y = MF(m[6], Wnf, bR); y = MF(m[7], If, y); f32x4 aR = MF(m[8], Af, y);
    u = MF(g[2][0], Wnf, bMI); f32x4 aMI = MF(g[2][1], Af, u);        // img over [W_new, A]
    f32x4 zz, ri, mi;
#pragma unroll
    for (int r = 0; r < 4; ++r) {
      zz[r] = sg(aZ[r]);
      ri[r] = sg(aR[r]) * iv[r];
      mi[r] = sg(aMI[r]);
    }
    u32x2 ri2 = pkx(ri);
    xb[1][tid] = pack64(ri2); __syncthreads();
    s16x8 rIf = frag(ri2, unpack64(xb[1][tid ^ 64]), wv);

    // ---- phase C: h, I_new ----
    x = MF(m[9], Wnf, bH); x = MF(m[10], rIf, x); f32x4 aH = MF(m[11], Af, x);
    f32x4 inw;
#pragma unroll
    for (int r = 0; r < 4; ++r) {
      float hv = th(aH[r]);
      float tt = hv * mi[r];
      inw[r] = fmaf(zz[r], tt - iv[r], iv[r]);   // (1-z)*iv + z*h*mi
    }
    u32x2 in2 = pkx(inw);
    xb[2][tid] = pack64(in2); __syncthreads();
    s16x8 Inf = frag(in2, unpack64(xb[2][tid ^ 64]), wv);

    // ---- phase D: A_all, mult_A, A_new ----
    x = MF(m[12], Wnf, bA); x = MF(m[13], Inf, x); f32x4 aAl = MF(m[14], Af, x);  // -2L2E*Aall
    y = MF(g[3][0], Wnf, bMA); f32x4 aMA = MF(g[3][1], Inf, y);                    // amg over [W_new, I_new]
    f32x4 an;
#pragma unroll
    for (int r = 0; r < 4; ++r) {
      float ma = sg(aMA[r]);
      an[r] = th(aAl[r] * ma);
    }
    u32x2 an2 = pkx(an);
    xb[3][tid] = pack64(an2); __syncthreads();
    s16x8 Anf = frag(an2, unpack64(xb[3][tid ^ 64]), wv);

    // ---- phase E: action = phi(A_new) + phi_b (wave0 of pair; h=0 lanes) ----
    if (wv == 0) {
      f32x4 aP = MF(pf, Anf, pb);
      if (h == 0)
        *(f32x4*)(P.out + ((size_t)t*Bn + bbase + c) * 4) = aP;
    }

    // ---- rotate state ----
    Wf = Wnf; If = Inf; Af = Anf; iv = inw; ob = nb;
  }
}

extern "C" void kernel_launch(void* const* d_in, const int* in_sizes, int n_in,
                              void* d_out, int out_size, void* d_ws, size_t ws_size,
                              hipStream_t stream) {
  (void)in_sizes; (void)n_in; (void)d_ws; (void)ws_size; (void)out_size;
  Params p;
  p.obs   = (const float*)d_in[0];
  p.enc_w = (const float*)d_in[1];
  p.enc_b = (const float*)d_in[2];
  for (int i = 0; i < 15; ++i) p.mw[i] = (const float*)d_in[3 + i];
  for (int i = 0; i < 4; ++i) {
    p.gw[i] = (const float*)d_in[18 + 2*i];
    p.gb[i] = (const float*)d_in[19 + 2*i];
  }
  p.z_b   = (const float*)d_in[26];
  p.r_b   = (const float*)d_in[27];
  p.h_b   = (const float*)d_in[28];
  p.a_b   = (const float*)d_in[29];
  p.phi_w = (const float*)d_in[30];
  p.phi_b = (const float*)d_in[31];
  p.out   = (float*)d_out;

  hipLaunchKernelGGL(anima_kernel, dim3(Bn / 64), dim3(512), 0, stream, p);
}

// Round 13
// 390.201 us; speedup vs baseline: 1.6315x; 1.4065x over previous
//
#include <hip/hip_runtime.h>
#include <hip/hip_bf16.h>

typedef __attribute__((ext_vector_type(4))) float f32x4;
typedef __attribute__((ext_vector_type(8))) short s16x8;
typedef __attribute__((ext_vector_type(2))) unsigned int u32x2;
typedef __attribute__((ext_vector_type(4))) unsigned int u32x4;

#define DEV static __device__ __forceinline__

constexpr int Tn = 256, Bn = 1024, Sn = 8;
constexpr float L2E   =  1.44269504f;
constexpr float NL2E  = -1.44269504f;   // fold into sigmoid-arg weights
constexpr float N2L2E = -2.88539008f;   // fold into tanh-arg weights

struct Params {
  const float* obs; const float* enc_w; const float* enc_b;
  const float* mw[15];            // wW wI wA zW zI zA rW rI rA hW hI hA aW aI aA
  const float* gw[4];             // att wmg img amg  [32 x 64]
  const float* gb[4];
  const float* z_b; const float* r_b; const float* h_b; const float* a_b;
  const float* phi_w; const float* phi_b;
  float* out;
};

DEV f32x4 ld4(const float* p) { return *(const f32x4*)p; }
DEV f32x4 zero4() { f32x4 r = {0.f,0.f,0.f,0.f}; return r; }
DEV s16x8 zero8() { s16x8 r = {0,0,0,0,0,0,0,0}; return r; }

// packed f32->bf16 pair (RNE) -> v_cvt_pk_bf16_f32
DEV unsigned cvtpk(float a, float b) {
  __hip_bfloat162 t = __float22bfloat162_rn(make_float2(a, b));
  unsigned u; __builtin_memcpy(&u, &t, 4);
  return u;
}

// pack 8 scaled f32 into a bf16x8 fragment; elem e=0..3 <-> k=4h+e,
// e=4..7 <-> k=16+4h+(e-4)  [same k-map lambda on A and B sides]
DEV s16x8 pk2s(f32x4 a, f32x4 b, float s) {
  u32x4 f;
  f[0] = cvtpk(a[0]*s, a[1]*s); f[1] = cvtpk(a[2]*s, a[3]*s);
  f[2] = cvtpk(b[0]*s, b[1]*s); f[3] = cvtpk(b[2]*s, b[3]*s);
  s16x8 r; __builtin_memcpy(&r, &f, 16);
  return r;
}

// weight fragment (A-operand of swapped MFMA): lane (h,c) holds matrix row
// `row`, k-cols {kofs+4h..+3, kofs+16+4h..+3}; values pre-scaled by s.
DEV s16x8 wfrag(const float* w, int row, int ldk, int kofs, int h, float s) {
  const float* p = w + row*ldk + kofs + 4*h;
  return pk2s(ld4(p), ld4(p+16), s);
}

DEV f32x4 MF(s16x8 a, s16x8 b, f32x4 c) {
  return __builtin_amdgcn_mfma_f32_16x16x32_bf16(a, b, c, 0, 0, 0);
}

DEV float ex2(float x)  { return __builtin_amdgcn_exp2f(x); }
DEV float rcp_(float x) { return __builtin_amdgcn_rcpf(x); }
// activations with the scale already folded into the argument:
DEV float sg(float a) { return rcp_(1.f + ex2(a)); }                 // sigmoid(x), a=-L2E*x
DEV float th(float a) { return fmaf(rcp_(1.f + ex2(a)), 2.f, -1.f); } // tanh(x), a=-2L2E*x

DEV unsigned long long pack64(u32x2 v) {
  return ((unsigned long long)v[1] << 32) | v[0];
}
DEV u32x2 unpack64(unsigned long long x) {
  u32x2 r; r[0] = (unsigned)x; r[1] = (unsigned)(x >> 32); return r;
}
DEV u32x2 pkx(f32x4 v) {
  u32x2 r; r[0] = cvtpk(v[0], v[1]); r[1] = cvtpk(v[2], v[3]); return r;
}
// assemble full 32-k state fragment from own half + partner half
DEV s16x8 frag(u32x2 own, u32x2 oth, int wv) {
  u32x4 f;
  if (wv == 0) { f[0]=own[0]; f[1]=own[1]; f[2]=oth[0]; f[3]=oth[1]; }
  else         { f[0]=oth[0]; f[1]=oth[1]; f[2]=own[0]; f[3]=own[1]; }
  s16x8 r; __builtin_memcpy(&r, &f, 16);
  return r;
}

DEV f32x4 scl4(f32x4 v, float s) { f32x4 r; r[0]=v[0]*s; r[1]=v[1]*s; r[2]=v[2]*s; r[3]=v[3]*s; return r; }

// 2 waves/block (round-8 base, 294.7us). This round: latency-hiding schedule.
// Every accumulation chain is reassociated so the freshly-EXCHANGED operand
// comes LAST: the early part (I/A-dep, known from previous exchanges) issues
// in the barrier->read window, and one MFMA finishes the chain after the read.
// Phase A is pipelined across the loop boundary (fills windows 3-4).
__global__ __launch_bounds__(128, 1) void anima_kernel(Params P) {
  const int tid  = threadIdx.x;
  const int wv   = tid >> 6;
  const int lane = tid & 63;
  const int h = lane >> 4, c = lane & 15;
  const int bbase = blockIdx.x * 16;
  const int row = wv*16 + c;

  __shared__ unsigned long long xb[4][128];

  // ---- persistent weight fragments, own j-half only, scale pre-folded ----
  const float msc[15] = {N2L2E,N2L2E,N2L2E,  NL2E,NL2E,NL2E,  NL2E,NL2E,NL2E,
                         N2L2E,N2L2E,N2L2E,  N2L2E,N2L2E,N2L2E};
  s16x8 m[15];
#pragma unroll
  for (int i = 0; i < 15; ++i) m[i] = wfrag(P.mw[i], row, 32, 0, h, msc[i]);

  s16x8 g[4][2];   // att wmg img amg, k-chunks q=0,1
#pragma unroll
  for (int i = 0; i < 4; ++i)
#pragma unroll
    for (int q = 0; q < 2; ++q)
      g[i][q] = wfrag(P.gw[i], row, 64, 32*q, h, NL2E);

  s16x8 ef = zero8();          // encoder rows own-j, k 0..7 on h<2 lanes
  if (h < 2) { f32x4 v = ld4(P.enc_w + row*Sn + 4*h); ef = pk2s(v, zero4(), N2L2E); }

  s16x8 pf = (wv == 0 && c < 4) ? wfrag(P.phi_w, c, 32, 0, h, 1.0f) : zero8();

  const int o = wv*16 + 4*h;   // bias accum-init: outdim 16w+4h+r
  f32x4 bE  = scl4(ld4(P.enc_b + o), N2L2E);
  f32x4 bAt = scl4(ld4(P.gb[0] + o), NL2E);
  f32x4 bMu = scl4(ld4(P.gb[1] + o), NL2E);
  f32x4 bMI = scl4(ld4(P.gb[2] + o), NL2E);
  f32x4 bMA = scl4(ld4(P.gb[3] + o), NL2E);
  f32x4 bZ  = scl4(ld4(P.z_b + o),  NL2E);
  f32x4 bR  = scl4(ld4(P.r_b + o),  NL2E);
  f32x4 bH  = scl4(ld4(P.h_b + o),  N2L2E);
  f32x4 bA  = scl4(ld4(P.a_b + o),  N2L2E);
  f32x4 pb  = (wv == 0 && h == 0) ? ld4(P.phi_b) : zero4();

  // ---- state ----
  f32x4 iv = zero4();                 // I(t-1), own 4 dims, f32
  s16x8 Inf = zero8();                // I(t-1) full fragment
  u32x2 an2; an2[0] = 0u; an2[1] = 0u; // own A(t-1) half, packed bf16

  f32x4 ob = zero4(), obN = zero4();
  if (h < 2) ob  = ld4(P.obs + (size_t)(bbase + c) * Sn + 4*h);
  if (h < 2) obN = ld4(P.obs + ((size_t)1*Bn + bbase + c) * Sn + 4*h);
  s16x8 Of = (h < 2) ? pk2s(ob, zero4(), 1.0f) : zero8();

  // ---- early-A partials for t=0 (zero states => exact) ----
  f32x4 tA1 = zero4();     // wW*W + wI*I part of Wall
  f32x4 yAt = bAt;         // att pre
  f32x4 uMu = bMu;         // wmg I-part
  f32x4 aE  = MF(ef, Of, bE);

  xb[3][tid] = pack64(an2);
  __syncthreads();
  unsigned long long pw3 = xb[3][tid ^ 64];

#pragma unroll 1
  for (int t = 0; t < Tn; ++t) {
    // ---- finish phase A: A(t-1) arrives ----
    s16x8 Anf = frag(an2, unpack64(pw3), wv);
    if (wv == 0 && t) {
      f32x4 aP = MF(pf, Anf, pb);
      if (h == 0) *(f32x4*)(P.out + ((size_t)(t-1)*Bn + bbase + c) * 4) = aP;
    }
    f32x4 aWl = MF(m[2], Anf, tA1);
    f32x4 aMu = MF(g[1][1], Anf, uMu);
    f32x4 wn;
#pragma unroll
    for (int r = 0; r < 4; ++r) {
      float etp = fmaf(rcp_(1.f + ex2(aE[r])), -4.f*L2E, 2.f*L2E);  // -2L2E*tanh(enc)
      float at  = sg(yAt[r]);
      float mg  = sg(aMu[r]);
      wn[r] = th(fmaf(etp, at, aWl[r]*mg));
    }
    u32x2 wn2 = pkx(wn);
    xb[0][tid] = pack64(wn2);
    __syncthreads();
    unsigned long long pw0 = xb[0][tid ^ 64];          // read issued
    f32x4 eZ  = MF(m[5], Anf, MF(m[4], Inf, bZ));      // fill read latency
    f32x4 eR  = MF(m[8], Anf, MF(m[7], Inf, bR));
    f32x4 eMI = MF(g[2][1], Anf, bMI);
    s16x8 Wnew = frag(wn2, unpack64(pw0), wv);
    f32x4 aZ  = MF(m[3], Wnew, eZ);
    f32x4 aR  = MF(m[6], Wnew, eR);
    f32x4 aMI = MF(g[2][0], Wnew, eMI);
    f32x4 zz, ri, mi;
#pragma unroll
    for (int r = 0; r < 4; ++r) {
      zz[r] = sg(aZ[r]);
      ri[r] = sg(aR[r]) * iv[r];
      mi[r] = sg(aMI[r]);
    }
    u32x2 ri2 = pkx(ri);
    xb[1][tid] = pack64(ri2);
    __syncthreads();
    unsigned long long pw1 = xb[1][tid ^ 64];
    f32x4 eH  = MF(m[11], Anf, MF(m[9],  Wnew, bH));   // fill
    f32x4 eAl = MF(m[14], Anf, MF(m[12], Wnew, bA));
    f32x4 eMA = MF(g[3][0], Wnew, bMA);
    s16x8 rIf = frag(ri2, unpack64(pw1), wv);
    f32x4 aH = MF(m[10], rIf, eH);
    f32x4 inw;
#pragma unroll
    for (int r = 0; r < 4; ++r) {
      float hv = th(aH[r]);
      inw[r] = fmaf(zz[r], hv * mi[r] - iv[r], iv[r]);  // (1-z)*iv + z*h*mi
    }
    u32x2 in2 = pkx(inw);
    xb[2][tid] = pack64(in2);
    __syncthreads();
    unsigned long long pw2 = xb[2][tid ^ 64];
    f32x4 t0 = MF(m[0], Wnew, zero4());                // fill: next-A W-parts
    f32x4 y0 = MF(g[0][0], Wnew, bAt);
    s16x8 OfN = (h < 2) ? pk2s(obN, zero4(), 1.0f) : zero8();
    aE = MF(ef, OfN, bE);
    s16x8 Inew = frag(in2, unpack64(pw2), wv);
    f32x4 aAl = MF(m[13], Inew, eAl);
    f32x4 aMA = MF(g[3][1], Inew, eMA);
    f32x4 an;
#pragma unroll
    for (int r = 0; r < 4; ++r) an[r] = th(aAl[r] * sg(aMA[r]));
    an2 = pkx(an);
    xb[3][tid] = pack64(an2);
    __syncthreads();
    pw3 = xb[3][tid ^ 64];
    tA1 = MF(m[1], Inew, t0);                          // fill: next-A I-parts
    yAt = MF(g[0][1], Inew, y0);
    uMu = MF(g[1][0], Inew, bMu);
    if (h < 2 && t + 2 < Tn)
      obN = ld4(P.obs + ((size_t)(t+2)*Bn + bbase + c) * Sn + 4*h);
    Inf = Inew; iv = inw;
  }

  // ---- epilogue: phi(A(Tn-1)) ----
  s16x8 Anf = frag(an2, unpack64(pw3), wv);
  if (wv == 0) {
    f32x4 aP = MF(pf, Anf, pb);
    if (h == 0) *(f32x4*)(P.out + ((size_t)(Tn-1)*Bn + bbase + c) * 4) = aP;
  }
}

extern "C" void kernel_launch(void* const* d_in, const int* in_sizes, int n_in,
                              void* d_out, int out_size, void* d_ws, size_t ws_size,
                              hipStream_t stream) {
  (void)in_sizes; (void)n_in; (void)d_ws; (void)ws_size; (void)out_size;
  Params p;
  p.obs   = (const float*)d_in[0];
  p.enc_w = (const float*)d_in[1];
  p.enc_b = (const float*)d_in[2];
  for (int i = 0; i < 15; ++i) p.mw[i] = (const float*)d_in[3 + i];
  for (int i = 0; i < 4; ++i) {
    p.gw[i] = (const float*)d_in[18 + 2*i];
    p.gb[i] = (const float*)d_in[19 + 2*i];
  }
  p.z_b   = (const float*)d_in[26];
  p.r_b   = (const float*)d_in[27];
  p.h_b   = (const float*)d_in[28];
  p.a_b   = (const float*)d_in[29];
  p.phi_w = (const float*)d_in[30];
  p.phi_b = (const float*)d_in[31];
  p.out   = (float*)d_out;

  hipLaunchKernelGGL(anima_kernel, dim3(Bn / 16), dim3(128), 0, stream, p);
}